// Round 21
// baseline (425.368 us; speedup 1.0000x reference)
//
#include <hip/hip_runtime.h>
#include <math.h>

// Problem: B=32, C=192, H=W=32, CH=8, stride=2 -> FEAT=2048, N=C*C=36864
// Pipeline (4 kernels): conv -> linear(+hreduce fused, 4 K-quarter blocks) ->
//   LU(+combine fused; weight written to mats) -> out ; logdet.

#define NFEAT 2048
#define NN    36864

// ---------------- Stage 1: conv partials (c-sliced, spatial-split; R19 verified) ---
__global__ __launch_bounds__(256) void conv_kernel(const float* __restrict__ w,
                                                   const float* __restrict__ cw,
                                                   float* __restrict__ hpart) {
  int blk = blockIdx.x;
  int ph = blk & 1;
  int bc = blk >> 1;
  int b = bc >> 2, cs = bc & 3;
  int tid = threadIdx.x;
  int pix = tid & 127;           // 0..127 within half
  int chh = tid >> 7;            // 0..1 channel half
  int oy = (ph << 3) + (pix >> 4);
  int ox = pix & 15;
  __shared__ float wlds[8 * 48 * 9];
  for (int idx = tid; idx < 8 * 48 * 9; idx += 256) {
    int ch = idx / 432, rem = idx - ch * 432;
    int c = rem / 9, kk = rem - c * 9;
    wlds[idx] = cw[ch * 1728 + (cs * 48 + c) * 9 + kk];
  }
  __syncthreads();
  float acc[4];
#pragma unroll
  for (int j = 0; j < 4; ++j) acc[j] = 0.f;
  const float* img0 = w + (((size_t)b * 192 + cs * 48) << 10);
  for (int c = 0; c < 48; ++c) {
    const float* img = img0 + ((size_t)c << 10);
    float iv[9];
#pragma unroll
    for (int ky = 0; ky < 3; ++ky)
#pragma unroll
      for (int kx = 0; kx < 3; ++kx) {
        int iy = 2 * oy - 1 + ky, ix = 2 * ox - 1 + kx;
        bool ok = (iy >= 0) & (iy < 32) & (ix >= 0) & (ix < 32);
        iv[ky * 3 + kx] = ok ? img[iy * 32 + ix] : 0.f;
      }
#pragma unroll
    for (int j = 0; j < 4; ++j) {
      int ch = (chh << 2) + j;
      const float* wp = &wlds[(ch * 48 + c) * 9];
      float s = acc[j];
#pragma unroll
      for (int t = 0; t < 9; ++t) s = fmaf(iv[t], wp[t], s);
      acc[j] = s;
    }
  }
  size_t base = ((size_t)(cs * 32 + b) << 11) + (oy << 4) + ox;
#pragma unroll
  for (int j = 0; j < 4; ++j) hpart[base + ((size_t)((chh << 2) + j) << 8)] = acc[j];
}

// ---------------- Stage 2: linear v6 = v5 + fused hreduce --------------------------
// R21: H staged directly from hpart's 4 cs-slices using hreduce's EXACT expression
// (s=0; s+=p0..p3; s+=cb; fmax) -> Hbuf bits identical to the old h_bt; hreduce
// kernel removed. hpart (1MB) is L2-cached across blocks.
#define WROW(r) ((r) * 68 + (((r) >> 3) << 2))
__global__ __launch_bounds__(128) void linear_kernel(const float* __restrict__ hpart,
                                                     const float* __restrict__ cb,
                                                     const float* __restrict__ lw,
                                                     float* __restrict__ qpart) {
  __shared__ float Wbuf[8768];   // 128 rows, WROW layout (max idx 8759)
  __shared__ float Hbuf[2192];   // 32 rows, WROW layout (max idx 2183)
  int tid = threadIdx.x;
  int blk = blockIdx.x;
  int q = blk & 3;               // K quarter
  int tile = blk >> 2;           // 0..287
  int n0 = tile << 7;
  int kqb = q << 9;
  int bp = tid & 7;              // b-quad: owns b = 4bp .. 4bp+3
  int ng = tid >> 3;             // 0..15
  int nb = ng << 3;              // 8 n-rows
  int bb0 = bp << 2;
  float acc[32];
#pragma unroll
  for (int i = 0; i < 32; ++i) acc[i] = 0.f;

  for (int kc = 0; kc < 8; ++kc) {
    int koff = kqb + (kc << 6);
#pragma unroll
    for (int j = 0; j < 16; ++j) {
      int f = tid + (j << 7);
      int row = f >> 4, c4 = (f & 15) << 2;
      *(float4*)(Wbuf + WROW(row) + c4) =
          *(const float4*)(lw + (size_t)(n0 + row) * 2048 + koff + c4);
    }
#pragma unroll
    for (int j = 0; j < 4; ++j) {
      int f = tid + (j << 7);
      int bi = f >> 4, c4 = (f & 15) << 2;
      int kk2 = koff + c4;
      float4 p0 = *(const float4*)(hpart + (((size_t)(0 * 32 + bi)) << 11) + kk2);
      float4 p1 = *(const float4*)(hpart + (((size_t)(1 * 32 + bi)) << 11) + kk2);
      float4 p2 = *(const float4*)(hpart + (((size_t)(2 * 32 + bi)) << 11) + kk2);
      float4 p3 = *(const float4*)(hpart + (((size_t)(3 * 32 + bi)) << 11) + kk2);
      float cbv = cb[kk2 >> 8];
      float4 s;
      s.x = 0.f; s.x += p0.x; s.x += p1.x; s.x += p2.x; s.x += p3.x; s.x += cbv; s.x = fmaxf(s.x, 0.f);
      s.y = 0.f; s.y += p0.y; s.y += p1.y; s.y += p2.y; s.y += p3.y; s.y += cbv; s.y = fmaxf(s.y, 0.f);
      s.z = 0.f; s.z += p0.z; s.z += p1.z; s.z += p2.z; s.z += p3.z; s.z += cbv; s.z = fmaxf(s.z, 0.f);
      s.w = 0.f; s.w += p0.w; s.w += p1.w; s.w += p2.w; s.w += p3.w; s.w += cbv; s.w = fmaxf(s.w, 0.f);
      *(float4*)(Hbuf + WROW(bi) + c4) = s;
    }
    __syncthreads();
#pragma unroll 2
    for (int k4 = 0; k4 < 16; ++k4) {
      int kk = k4 << 2;
      float4 h0 = *(const float4*)(Hbuf + WROW(bb0 + 0) + kk);
      float4 h1 = *(const float4*)(Hbuf + WROW(bb0 + 1) + kk);
      float4 h2 = *(const float4*)(Hbuf + WROW(bb0 + 2) + kk);
      float4 h3 = *(const float4*)(Hbuf + WROW(bb0 + 3) + kk);
#pragma unroll
      for (int j = 0; j < 8; ++j) {
        float4 w4 = *(const float4*)(Wbuf + WROW(nb + j) + kk);
        float s0 = acc[j * 4 + 0], s1 = acc[j * 4 + 1];
        float s2 = acc[j * 4 + 2], s3 = acc[j * 4 + 3];
        s0 = fmaf(w4.x, h0.x, s0); s0 = fmaf(w4.y, h0.y, s0);
        s0 = fmaf(w4.z, h0.z, s0); s0 = fmaf(w4.w, h0.w, s0);
        s1 = fmaf(w4.x, h1.x, s1); s1 = fmaf(w4.y, h1.y, s1);
        s1 = fmaf(w4.z, h1.z, s1); s1 = fmaf(w4.w, h1.w, s1);
        s2 = fmaf(w4.x, h2.x, s2); s2 = fmaf(w4.y, h2.y, s2);
        s2 = fmaf(w4.z, h2.z, s2); s2 = fmaf(w4.w, h2.w, s2);
        s3 = fmaf(w4.x, h3.x, s3); s3 = fmaf(w4.y, h3.y, s3);
        s3 = fmaf(w4.z, h3.z, s3); s3 = fmaf(w4.w, h3.w, s3);
        acc[j * 4 + 0] = s0; acc[j * 4 + 1] = s1;
        acc[j * 4 + 2] = s2; acc[j * 4 + 3] = s3;
      }
    }
    __syncthreads();
  }
#pragma unroll
  for (int i = 0; i < 4; ++i) {
    float* p = qpart + (size_t)q * 1179648 + (size_t)(bb0 + i) * NN + n0 + nb;
    *(float4*)(p + 0) = make_float4(acc[0 * 4 + i], acc[1 * 4 + i], acc[2 * 4 + i], acc[3 * 4 + i]);
    *(float4*)(p + 4) = make_float4(acc[4 * 4 + i], acc[5 * 4 + i], acc[6 * 4 + i], acc[7 * 4 + i]);
  }
}

// ---------------- Stage 3: BLOCKED LU NB=8 + fused combine (R20 core verified) -----
// R21: load phase combines ((q0+q1)+q2)+q3 + lb from qpart (bits == old combine);
// epilogue re-combines the same expression for its base and writes weight to mats
// as a PURE write. combine kernel removed. LU core = R20 (lookahead, fused TRSM,
// balanced phase-B). absmax must stay exactly 4194304.
#define CAT_(A, B) A##B
#define CAT(A, B) CAT_(A, B)
#define PR_0(R) CAT(pA, R).x
#define PR_1(R) CAT(pA, R).y
#define PR_2(R) CAT(pA, R).z
#define PR_3(R) CAT(pA, R).w
#define PR_4(R) CAT(pB, R).x
#define PR_5(R) CAT(pB, R).y
#define PR_6(R) CAT(pB, R).z
#define PR_7(R) CAT(pB, R).w
#define PR(R, K) CAT(PR_, K)(R)
#define UU_0 uA.x
#define UU_1 uA.y
#define UU_2 uA.z
#define UU_3 uA.w
#define UU_4 uB.x
#define UU_5 uB.y
#define UU_6 uB.z
#define UU_7 uB.w
#define UU(K) CAT(UU_, K)
#define UPDJ(R, J) PR(R, J) = fmaf(-m, UU(J), PR(R, J));
#define TAIL_0(R) UPDJ(R,1) UPDJ(R,2) UPDJ(R,3) UPDJ(R,4) UPDJ(R,5) UPDJ(R,6) UPDJ(R,7)
#define TAIL_1(R) UPDJ(R,2) UPDJ(R,3) UPDJ(R,4) UPDJ(R,5) UPDJ(R,6) UPDJ(R,7)
#define TAIL_2(R) UPDJ(R,3) UPDJ(R,4) UPDJ(R,5) UPDJ(R,6) UPDJ(R,7)
#define TAIL_3(R) UPDJ(R,4) UPDJ(R,5) UPDJ(R,6) UPDJ(R,7)
#define TAIL_4(R) UPDJ(R,5) UPDJ(R,6) UPDJ(R,7)
#define TAIL_5(R) UPDJ(R,6) UPDJ(R,7)
#define TAIL_6(R) UPDJ(R,7)
#define TAIL_7(R)
#define UPDROW(R, KK, kg)                                                      \
  if (CAT(lg, R) > (kg)) {                                                     \
    float m = PR(R, KK) * recip;                                               \
    PR(R, KK) = m;                                                             \
    CAT(TAIL_, KK)(R)                                                          \
  }
#define PSTEP(KK) {                                                            \
  const int kg = kpP + KK;                                                     \
  float bv = -1.f; int br = 0x7fffffff;                                        \
  { float v = fabsf(PR(0,KK)); if (lg0 >= kg && (v > bv || (v == bv && lg0 < br))) { bv = v; br = lg0; } } \
  { float v = fabsf(PR(1,KK)); if (lg1 >= kg && (v > bv || (v == bv && lg1 < br))) { bv = v; br = lg1; } } \
  { float v = fabsf(PR(2,KK)); if (lg2 >= kg && (v > bv || (v == bv && lg2 < br))) { bv = v; br = lg2; } } \
  for (int msk = 1; msk <= 32; msk <<= 1) {                                    \
    float ov = __shfl_xor(bv, msk, 64);                                        \
    int obr = __shfl_xor(br, msk, 64);                                         \
    if (ov > bv || (ov == bv && obr < br)) { bv = ov; br = obr; }              \
  }                                                                            \
  bool own0 = (lg0 == br), own1 = (lg1 == br), own2 = (lg2 == br);             \
  float4 sA = own1 ? pA1 : (own2 ? pA2 : pA0);                                 \
  float4 sB = own1 ? pB1 : (own2 ? pB2 : pB0);                                 \
  int owner = (int)__ffsll(__ballot(own0 | own1 | own2)) - 1;                  \
  float4 uA, uB;                                                               \
  uA.x = __shfl(sA.x, owner); uA.y = __shfl(sA.y, owner);                      \
  uA.z = __shfl(sA.z, owner); uA.w = __shfl(sA.w, owner);                      \
  uB.x = __shfl(sB.x, owner); uB.y = __shfl(sB.y, owner);                      \
  uB.z = __shfl(sB.z, owner); uB.w = __shfl(sB.w, owner);                      \
  float piv = UU(KK);                                                          \
  float recip = 1.0f / piv;                                                    \
  if (tid == 0) {                                                              \
    diagU[kg] = piv;                                                           \
    int t0 = rowmap[kg], t1 = rowmap[br];                                      \
    rowmap[kg] = t1; rowmap[br] = t0;                                          \
  }                                                                            \
  lg0 = (lg0 == kg) ? br : ((lg0 == br) ? kg : lg0);                           \
  lg1 = (lg1 == kg) ? br : ((lg1 == br) ? kg : lg1);                           \
  lg2 = (lg2 == kg) ? br : ((lg2 == br) ? kg : lg2);                           \
  UPDROW(0, KK, kg)                                                            \
  UPDROW(1, KK, kg)                                                            \
  UPDROW(2, KK, kg)                                                            \
}
#define FMA4(D, M, S) {                                                        \
  float mm = (M);                                                              \
  D.x = fmaf(-mm, S.x, D.x); D.y = fmaf(-mm, S.y, D.y);                        \
  D.z = fmaf(-mm, S.z, D.z); D.w = fmaf(-mm, S.w, D.w);                        \
}
// panel factorization of cols [KPV, KPV+8), wave 0 only, all in registers
#define PANEL(KPV) {                                                           \
  const int kpP = (KPV);                                                       \
  const int pcP = kpP >> 2;                                                    \
  float4 pA0 = As4[tid * 49 + pcP],         pB0 = As4[tid * 49 + pcP + 1];     \
  float4 pA1 = As4[(tid + 64) * 49 + pcP],  pB1 = As4[(tid + 64) * 49 + pcP + 1]; \
  float4 pA2 = As4[(tid + 128) * 49 + pcP], pB2 = As4[(tid + 128) * 49 + pcP + 1]; \
  PSTEP(0) PSTEP(1) PSTEP(2) PSTEP(3) PSTEP(4) PSTEP(5) PSTEP(6) PSTEP(7)     \
  As4[tid * 49 + pcP] = pA0;         As4[tid * 49 + pcP + 1] = pB0;            \
  As4[(tid + 64) * 49 + pcP] = pA1;  As4[(tid + 64) * 49 + pcP + 1] = pB1;     \
  As4[(tid + 128) * 49 + pcP] = pA2; As4[(tid + 128) * 49 + pcP + 1] = pB2;    \
}
// TRSM of the 8 u-rows for chunk COLQ, entirely in registers (defines u40..u47).
#define TRSM8REG(U0, U1, U2, U3, U4, U5, U6, U7, COLQ)                         \
  float4 u40 = As4[U0 * 49 + (COLQ)], u41 = As4[U1 * 49 + (COLQ)];             \
  float4 u42 = As4[U2 * 49 + (COLQ)], u43 = As4[U3 * 49 + (COLQ)];             \
  float4 u44 = As4[U4 * 49 + (COLQ)], u45 = As4[U5 * 49 + (COLQ)];             \
  float4 u46 = As4[U6 * 49 + (COLQ)], u47 = As4[U7 * 49 + (COLQ)];             \
  { float4 la = As4[U1 * 49 + pc];                                             \
    FMA4(u41, la.x, u40) }                                                     \
  { float4 la = As4[U2 * 49 + pc];                                             \
    FMA4(u42, la.x, u40) FMA4(u42, la.y, u41) }                                \
  { float4 la = As4[U3 * 49 + pc];                                             \
    FMA4(u43, la.x, u40) FMA4(u43, la.y, u41) FMA4(u43, la.z, u42) }           \
  { float4 la = As4[U4 * 49 + pc];                                             \
    FMA4(u44, la.x, u40) FMA4(u44, la.y, u41) FMA4(u44, la.z, u42) FMA4(u44, la.w, u43) } \
  { float4 la = As4[U5 * 49 + pc]; float4 lb2 = As4[U5 * 49 + pc + 1];         \
    FMA4(u45, la.x, u40) FMA4(u45, la.y, u41) FMA4(u45, la.z, u42) FMA4(u45, la.w, u43) \
    FMA4(u45, lb2.x, u44) }                                                    \
  { float4 la = As4[U6 * 49 + pc]; float4 lb2 = As4[U6 * 49 + pc + 1];         \
    FMA4(u46, la.x, u40) FMA4(u46, la.y, u41) FMA4(u46, la.z, u42) FMA4(u46, la.w, u43) \
    FMA4(u46, lb2.x, u44) FMA4(u46, lb2.y, u45) }                              \
  { float4 la = As4[U7 * 49 + pc]; float4 lb2 = As4[U7 * 49 + pc + 1];         \
    FMA4(u47, la.x, u40) FMA4(u47, la.y, u41) FMA4(u47, la.z, u42) FMA4(u47, la.w, u43) \
    FMA4(u47, lb2.x, u44) FMA4(u47, lb2.y, u45) FMA4(u47, lb2.z, u46) }

__global__ __launch_bounds__(768, 1) void lu_kernel(const float* __restrict__ qpart,
                                                    const float* __restrict__ lbp,
                                                    const float* __restrict__ ssign,
                                                    float* __restrict__ ssum,
                                                    float* __restrict__ mats) {
  __shared__ float4 As4[192 * 49];     // 150528 B, row stride 49 float4
  __shared__ int rowmap[192];
  __shared__ float diagU[192];
  __shared__ float4 dval4[48];
  float* dvalf = (float*)dval4;
  int b = blockIdx.x;
  int tid = threadIdx.x;
  float* __restrict__ A = mats + (size_t)b * NN;   // weight output (pure write)
  const size_t qb = (size_t)b * NN;

  // load A -> LDS with fused combine: ((q0+q1)+q2)+q3 + lb  (bits == old combine)
#pragma unroll
  for (int j = 0; j < 12; ++j) {
    int chunk = tid + 768 * j;
    int row = chunk / 48, q = chunk - row * 48;
    size_t n = (size_t)row * 192 + 4 * q;
    float4 q0 = *(const float4*)(qpart + 0 * 1179648 + qb + n);
    float4 q1 = *(const float4*)(qpart + 1 * 1179648 + qb + n);
    float4 q2 = *(const float4*)(qpart + 2 * 1179648 + qb + n);
    float4 q3 = *(const float4*)(qpart + 3 * 1179648 + qb + n);
    float4 bb2 = *(const float4*)(lbp + n);
    float4 m;
    m.x = ((q0.x + q1.x) + q2.x) + q3.x + bb2.x;
    m.y = ((q0.y + q1.y) + q2.y) + q3.y + bb2.y;
    m.z = ((q0.z + q1.z) + q2.z) + q3.z + bb2.z;
    m.w = ((q0.w + q1.w) + q2.w) + q3.w + bb2.w;
    As4[row * 49 + q] = m;
  }
  for (int i = tid; i < 192; i += 768) rowmap[i] = i;
  __syncthreads();

  int lg0 = tid, lg1 = tid + 64, lg2 = tid + 128;   // logical pos of wave0's rows

  // prologue: factorize panel 0
  if (tid < 64) { PANEL(0) }
  __syncthreads();

  const int slot = tid & 15;

  for (int p = 0; p < 23; ++p) {
    const int kp = p << 3;
    const int pc = kp >> 2;
    const int qp1 = pc + 2;      // first trailing chunk (= next panel's cols)

    // ---- phase A: TRSM-in-reg + GEMM next panel's 2 chunk cols + snapshot ----
    {
      const int col = qp1 + (tid >= 384 ? 1 : 0);
      const int rsl = tid - (tid >= 384 ? 384 : 0);
      const int s = kp + 8 + rsl;
      if (s < 192) {
        const int ua0 = rowmap[kp + 0], ua1 = rowmap[kp + 1];
        const int ua2 = rowmap[kp + 2], ua3 = rowmap[kp + 3];
        const int ua4 = rowmap[kp + 4], ua5 = rowmap[kp + 5];
        const int ua6 = rowmap[kp + 6], ua7 = rowmap[kp + 7];
        TRSM8REG(ua0, ua1, ua2, ua3, ua4, ua5, ua6, ua7, col)
        int phys = rowmap[s];
        float4 la = As4[phys * 49 + pc];
        float4 lb2 = As4[phys * 49 + pc + 1];
        float4 c = As4[phys * 49 + col];
        FMA4(c, la.x, u40) FMA4(c, la.y, u41) FMA4(c, la.z, u42) FMA4(c, la.w, u43)
        FMA4(c, lb2.x, u44) FMA4(c, lb2.y, u45) FMA4(c, lb2.z, u46) FMA4(c, lb2.w, u47)
        As4[phys * 49 + col] = c;
      }
    }
    // snapshot phys rows for phase B (named regs; rowmap stable until bar1)
    int php0, php1, php2, php3, php4, php5, php6, php7, php8, php9, php10, php11;
#define SNAP(I) CAT(php, I) = rowmap[slot + (I << 4)];
    SNAP(0) SNAP(1) SNAP(2) SNAP(3) SNAP(4) SNAP(5) SNAP(6)
    SNAP(7) SNAP(8) SNAP(9) SNAP(10) SNAP(11)
#undef SNAP
    __syncthreads();  // bar1: next-panel cols GEMM'd; snapshots taken

    // ---- phase B: wave0 panel p+1 || others balanced TRSM+GEMM ----
    if (tid < 64) {
      PANEL(kp + 8)
    } else {
      const int ncols = 44 - pc;            // trailing chunk cols pc+4..47
      if (ncols > 0) {
        const int g = (tid >> 4) - 4;       // 0..43
        const int nparts = 44 / ncols;      // >= 1
        const int part = g / ncols;
        const int colIdx = g - part * ncols;
        if (part < nparts) {
          const int q = pc + 4 + colIdx;
          const int ub0 = rowmap[kp + 0], ub1 = rowmap[kp + 1];
          const int ub2 = rowmap[kp + 2], ub3 = rowmap[kp + 3];
          const int ub4 = rowmap[kp + 4], ub5 = rowmap[kp + 5];
          const int ub6 = rowmap[kp + 6], ub7 = rowmap[kp + 7];
          TRSM8REG(ub0, ub1, ub2, ub3, ub4, ub5, ub6, ub7, q)
#define GEMMROW(I) {                                                           \
          int s = slot + (I << 4);                                             \
          if ((I % nparts) == part && s >= kp + 8) {                           \
            int phys = CAT(php, I);                                            \
            float4 la = As4[phys * 49 + pc];                                   \
            float4 lb2 = As4[phys * 49 + pc + 1];                              \
            float4 c = As4[phys * 49 + q];                                     \
            FMA4(c, la.x, u40) FMA4(c, la.y, u41) FMA4(c, la.z, u42) FMA4(c, la.w, u43) \
            FMA4(c, lb2.x, u44) FMA4(c, lb2.y, u45) FMA4(c, lb2.z, u46) FMA4(c, lb2.w, u47) \
            As4[phys * 49 + q] = c;                                            \
          }                                                                    \
        }
          GEMMROW(0) GEMMROW(1) GEMMROW(2) GEMMROW(3) GEMMROW(4) GEMMROW(5)
          GEMMROW(6) GEMMROW(7) GEMMROW(8) GEMMROW(9) GEMMROW(10) GEMMROW(11)
#undef GEMMROW
        }
      }
    }
    __syncthreads();  // bar2: panel p+1 factorized; trailing(p) complete
  }

  // ---- epilogue: logdet partial, dval, weight = combined(qpart,lb) + P*(L*diag(d))
  if (tid == 0) {
    float s = 0.f;
    for (int i = 0; i < 192; ++i) s += diagU[i];
    ssum[b] = s;
  }
  if (tid < 192) dvalf[tid] = ssign[tid] * expf(diagU[tid]) - diagU[tid];
  __syncthreads();
  {
    const int r = tid >> 2;
    const int tq = tid & 3;
    int i = r;
    int phys = rowmap[r];
    float di = dvalf[i];
    float* __restrict__ G = A + (size_t)phys * 192;   // output row = original row phys
    int qi = i >> 2;
    for (int j = 0; j < 12; ++j) {
      int q = tq + 4 * j;
      if (q > qi) continue;
      size_t n = (size_t)phys * 192 + 4 * q;
      float4 e0 = *(const float4*)(qpart + 0 * 1179648 + qb + n);
      float4 e1 = *(const float4*)(qpart + 1 * 1179648 + qb + n);
      float4 e2 = *(const float4*)(qpart + 2 * 1179648 + qb + n);
      float4 e3 = *(const float4*)(qpart + 3 * 1179648 + qb + n);
      float4 bb2 = *(const float4*)(lbp + n);
      float4 g4;
      g4.x = ((e0.x + e1.x) + e2.x) + e3.x + bb2.x;
      g4.y = ((e0.y + e1.y) + e2.y) + e3.y + bb2.y;
      g4.z = ((e0.z + e1.z) + e2.z) + e3.z + bb2.z;
      g4.w = ((e0.w + e1.w) + e2.w) + e3.w + bb2.w;
      float4 a4 = As4[phys * 49 + q];
      float4 d4 = dval4[q];
      if (q == qi) {                              // boundary chunk: per-element
        int c0 = 4 * q;
        g4.x = (c0 + 0 < i) ? g4.x + a4.x * d4.x : ((c0 + 0 == i) ? g4.x + di : g4.x);
        g4.y = (c0 + 1 < i) ? g4.y + a4.y * d4.y : ((c0 + 1 == i) ? g4.y + di : g4.y);
        g4.z = (c0 + 2 < i) ? g4.z + a4.z * d4.z : ((c0 + 2 == i) ? g4.z + di : g4.z);
        g4.w = (c0 + 3 < i) ? g4.w + a4.w * d4.w : ((c0 + 3 == i) ? g4.w + di : g4.w);
      } else {                                    // full chunk: all cols < i
        g4.x += a4.x * d4.x;
        g4.y += a4.y * d4.y;
        g4.z += a4.z * d4.z;
        g4.w += a4.w * d4.w;
      }
      *(float4*)(G + 4 * q) = g4;
    }
    // rows with no cols <= i still need upper part written? No: weight row phys
    // has entries for ALL cols; cols > i come from U (already in As4? no --
    // weight = mats + P*L*diag(d) only modifies cols <= i; cols > i equal mats).
    for (int j = 0; j < 12; ++j) {
      int q = tq + 4 * j;
      if (q <= qi) continue;
      size_t n = (size_t)phys * 192 + 4 * q;
      float4 e0 = *(const float4*)(qpart + 0 * 1179648 + qb + n);
      float4 e1 = *(const float4*)(qpart + 1 * 1179648 + qb + n);
      float4 e2 = *(const float4*)(qpart + 2 * 1179648 + qb + n);
      float4 e3 = *(const float4*)(qpart + 3 * 1179648 + qb + n);
      float4 bb2 = *(const float4*)(lbp + n);
      float4 g4;
      g4.x = ((e0.x + e1.x) + e2.x) + e3.x + bb2.x;
      g4.y = ((e0.y + e1.y) + e2.y) + e3.y + bb2.y;
      g4.z = ((e0.z + e1.z) + e2.z) + e3.z + bb2.z;
      g4.w = ((e0.w + e1.w) + e2.w) + e3.w + bb2.w;
      *(float4*)(G + 4 * q) = g4;
    }
  }
}

// ---------------- Stage 4: out[b] = weight[b] @ inp[b]  (+ logdet write) ----------
// (R19 verified: W transposed staging, 3 LDS instr / 32 FMA, bit-exact)
__global__ __launch_bounds__(256) void out_kernel(const float* __restrict__ wt,
                                                  const float* __restrict__ inp,
                                                  const float* __restrict__ ssum,
                                                  float* __restrict__ out) {
  int blk = blockIdx.x;
  int b = blk / 24, rem = blk % 24;
  int it = rem >> 3, jt = rem & 7;
  int i0 = it << 6, hw0 = jt << 7;
  int tid = threadIdx.x;
  int tx = tid & 31, ty = tid >> 5;
  __shared__ float wldsT[32 * 68];   // [k][i] transposed, stride 68 (16B-aligned)
  __shared__ float xlds[32 * 128];
  const float* wb = wt + (size_t)b * NN;
  const float* xb = inp + (((size_t)b * 192) << 10);
  float acc[8][4];
#pragma unroll
  for (int r = 0; r < 8; ++r)
#pragma unroll
    for (int c = 0; c < 4; ++c) acc[r][c] = 0.f;
  for (int kc = 0; kc < 6; ++kc) {
    __syncthreads();
#pragma unroll
    for (int j = 0; j < 2; ++j) {
      int f4 = tid + (j << 8);
      int row = f4 >> 3, c4 = (f4 & 7) << 2;
      float4 v = *(const float4*)(wb + (size_t)(i0 + row) * 192 + (kc << 5) + c4);
      wldsT[(c4 + 0) * 68 + row] = v.x;
      wldsT[(c4 + 1) * 68 + row] = v.y;
      wldsT[(c4 + 2) * 68 + row] = v.z;
      wldsT[(c4 + 3) * 68 + row] = v.w;
    }
#pragma unroll
    for (int j = 0; j < 4; ++j) {
      int f4 = tid + (j << 8);
      int row = f4 >> 5, c4 = (f4 & 31) << 2;
      float4 v = *(const float4*)(xb + (((size_t)(kc << 5) + row) << 10) + hw0 + c4);
      *(float4*)(xlds + (row << 7) + c4) = v;
    }
    __syncthreads();
#pragma unroll 4
    for (int k = 0; k < 32; ++k) {
      float4 xv = *(const float4*)(xlds + (k << 7) + (tx << 2));
      float4 wa = *(const float4*)(wldsT + k * 68 + ty * 8);
      float4 wbv = *(const float4*)(wldsT + k * 68 + ty * 8 + 4);
      acc[0][0] = fmaf(wa.x, xv.x, acc[0][0]);
      acc[0][1] = fmaf(wa.x, xv.y, acc[0][1]);
      acc[0][2] = fmaf(wa.x, xv.z, acc[0][2]);
      acc[0][3] = fmaf(wa.x, xv.w, acc[0][3]);
      acc[1][0] = fmaf(wa.y, xv.x, acc[1][0]);
      acc[1][1] = fmaf(wa.y, xv.y, acc[1][1]);
      acc[1][2] = fmaf(wa.y, xv.z, acc[1][2]);
      acc[1][3] = fmaf(wa.y, xv.w, acc[1][3]);
      acc[2][0] = fmaf(wa.z, xv.x, acc[2][0]);
      acc[2][1] = fmaf(wa.z, xv.y, acc[2][1]);
      acc[2][2] = fmaf(wa.z, xv.z, acc[2][2]);
      acc[2][3] = fmaf(wa.z, xv.w, acc[2][3]);
      acc[3][0] = fmaf(wa.w, xv.x, acc[3][0]);
      acc[3][1] = fmaf(wa.w, xv.y, acc[3][1]);
      acc[3][2] = fmaf(wa.w, xv.z, acc[3][2]);
      acc[3][3] = fmaf(wa.w, xv.w, acc[3][3]);
      acc[4][0] = fmaf(wbv.x, xv.x, acc[4][0]);
      acc[4][1] = fmaf(wbv.x, xv.y, acc[4][1]);
      acc[4][2] = fmaf(wbv.x, xv.z, acc[4][2]);
      acc[4][3] = fmaf(wbv.x, xv.w, acc[4][3]);
      acc[5][0] = fmaf(wbv.y, xv.x, acc[5][0]);
      acc[5][1] = fmaf(wbv.y, xv.y, acc[5][1]);
      acc[5][2] = fmaf(wbv.y, xv.z, acc[5][2]);
      acc[5][3] = fmaf(wbv.y, xv.w, acc[5][3]);
      acc[6][0] = fmaf(wbv.z, xv.x, acc[6][0]);
      acc[6][1] = fmaf(wbv.z, xv.y, acc[6][1]);
      acc[6][2] = fmaf(wbv.z, xv.z, acc[6][2]);
      acc[6][3] = fmaf(wbv.z, xv.w, acc[6][3]);
      acc[7][0] = fmaf(wbv.w, xv.x, acc[7][0]);
      acc[7][1] = fmaf(wbv.w, xv.y, acc[7][1]);
      acc[7][2] = fmaf(wbv.w, xv.z, acc[7][2]);
      acc[7][3] = fmaf(wbv.w, xv.w, acc[7][3]);
    }
  }
  float* ob = out + (((size_t)b * 192 + i0 + ty * 8) << 10) + hw0 + (tx << 2);
#pragma unroll
  for (int r = 0; r < 8; ++r) {
    float4 v = make_float4(acc[r][0], acc[r][1], acc[r][2], acc[r][3]);
    *(float4*)(ob + ((size_t)r << 10)) = v;
  }
  if (blk == 0 && tid == 0) {
    float s = 0.f;
    for (int i = 0; i < 32; ++i) s += ssum[i];
    out[6291456] = 32.f * s;   // H*W * mean over batch of sum(s)
  }
}

extern "C" void kernel_launch(void* const* d_in, const int* in_sizes, int n_in,
                              void* d_out, int out_size, void* d_ws, size_t ws_size,
                              hipStream_t stream) {
  const float* inp = (const float*)d_in[0];
  const float* wlo = (const float*)d_in[1];
  const float* cw  = (const float*)d_in[2];
  const float* cb  = (const float*)d_in[3];
  const float* lw  = (const float*)d_in[4];
  const float* lb  = (const float*)d_in[5];
  const float* ss  = (const float*)d_in[6];
  float* out = (float*)d_out;
  float* ws = (float*)d_ws;
  // ws layout (floats): hpart 262144 | (unused 65536) | mats 1179648 | ssum 32
  // quarter partials (18.9 MB) live in d_out and are overwritten by out_kernel.
  float* hpart = ws;
  float* mats  = ws + 327680;
  float* ssum  = ws + 1507328;
  float* qpart = out;
  hipLaunchKernelGGL(conv_kernel,   dim3(256),  dim3(256), 0, stream, wlo, cw, hpart);
  hipLaunchKernelGGL(linear_kernel, dim3(1152), dim3(128), 0, stream, hpart, cb, lw, qpart);
  hipLaunchKernelGGL(lu_kernel,     dim3(32),   dim3(768), 0, stream, qpart, lb, ss, ssum, mats);
  hipLaunchKernelGGL(out_kernel,    dim3(768),  dim3(256), 0, stream, mats, inp, ssum, out);
}

// Round 22
// 393.214 us; speedup vs baseline: 1.0818x; 1.0818x over previous
//
#include <hip/hip_runtime.h>
#include <math.h>

// Problem: B=32, C=192, H=W=32, CH=8, stride=2 -> FEAT=2048, N=C*C=36864
// Pipeline: conv(+relu) -> linear(4 K-quarter blocks) -> combine -> per-batch LU ->
//           weight = mats + P*(L*diag(d)) in-place -> out = weight @ inp ; logdet.
// R22 = exact revert to R20 (best verified: 394.9us). R21's fusion experiment
// regressed (+30us: lu FETCH 2.6->10.1MB from 4x qpart re-reads) and was dropped.

#define NFEAT 2048
#define NN    36864

// ---------------- Stage 1: conv partials (c-sliced, spatial-split; R19 verified) ---
__global__ __launch_bounds__(256) void conv_kernel(const float* __restrict__ w,
                                                   const float* __restrict__ cw,
                                                   float* __restrict__ hpart) {
  int blk = blockIdx.x;
  int ph = blk & 1;
  int bc = blk >> 1;
  int b = bc >> 2, cs = bc & 3;
  int tid = threadIdx.x;
  int pix = tid & 127;           // 0..127 within half
  int chh = tid >> 7;            // 0..1 channel half
  int oy = (ph << 3) + (pix >> 4);
  int ox = pix & 15;
  __shared__ float wlds[8 * 48 * 9];
  for (int idx = tid; idx < 8 * 48 * 9; idx += 256) {
    int ch = idx / 432, rem = idx - ch * 432;
    int c = rem / 9, kk = rem - c * 9;
    wlds[idx] = cw[ch * 1728 + (cs * 48 + c) * 9 + kk];
  }
  __syncthreads();
  float acc[4];
#pragma unroll
  for (int j = 0; j < 4; ++j) acc[j] = 0.f;
  const float* img0 = w + (((size_t)b * 192 + cs * 48) << 10);
  for (int c = 0; c < 48; ++c) {
    const float* img = img0 + ((size_t)c << 10);
    float iv[9];
#pragma unroll
    for (int ky = 0; ky < 3; ++ky)
#pragma unroll
      for (int kx = 0; kx < 3; ++kx) {
        int iy = 2 * oy - 1 + ky, ix = 2 * ox - 1 + kx;
        bool ok = (iy >= 0) & (iy < 32) & (ix >= 0) & (ix < 32);
        iv[ky * 3 + kx] = ok ? img[iy * 32 + ix] : 0.f;
      }
#pragma unroll
    for (int j = 0; j < 4; ++j) {
      int ch = (chh << 2) + j;
      const float* wp = &wlds[(ch * 48 + c) * 9];
      float s = acc[j];
#pragma unroll
      for (int t = 0; t < 9; ++t) s = fmaf(iv[t], wp[t], s);
      acc[j] = s;
    }
  }
  size_t base = ((size_t)(cs * 32 + b) << 11) + (oy << 4) + ox;
#pragma unroll
  for (int j = 0; j < 4; ++j) hpart[base + ((size_t)((chh << 2) + j) << 8)] = acc[j];
}

// ---------------- Stage 2: reduce partials + bias + relu -> h_bt[b][k] -------------
__global__ __launch_bounds__(256) void hreduce_kernel(const float* __restrict__ hpart,
                                                      const float* __restrict__ cb,
                                                      float* __restrict__ h_bt) {
  int g = blockIdx.x * 256 + threadIdx.x;   // 0..65535
  int k = g & 2047, b = g >> 11;
  float s = 0.f;
#pragma unroll
  for (int cs = 0; cs < 4; ++cs) s += hpart[(((size_t)(cs * 32 + b)) << 11) + k];
  s += cb[k >> 8];
  s = fmaxf(s, 0.f);
  h_bt[g] = s;   // g = b*2048 + k  (coalesced)
}

// ---------------- Stage 3: linear v5 (verified R16, bit-exact) ---------------------
#define WROW(r) ((r) * 68 + (((r) >> 3) << 2))
__global__ __launch_bounds__(128) void linear_kernel(const float* __restrict__ h_bt,
                                                     const float* __restrict__ lw,
                                                     float* __restrict__ qpart) {
  __shared__ float Wbuf[8768];   // 128 rows, WROW layout (max idx 8759)
  __shared__ float Hbuf[2192];   // 32 rows, WROW layout (max idx 2183)
  int tid = threadIdx.x;
  int blk = blockIdx.x;
  int q = blk & 3;               // K quarter
  int tile = blk >> 2;           // 0..287
  int n0 = tile << 7;
  int kqb = q << 9;
  int bp = tid & 7;              // b-quad: owns b = 4bp .. 4bp+3
  int ng = tid >> 3;             // 0..15
  int nb = ng << 3;              // 8 n-rows
  int bb0 = bp << 2;
  float acc[32];
#pragma unroll
  for (int i = 0; i < 32; ++i) acc[i] = 0.f;

  for (int kc = 0; kc < 8; ++kc) {
    int koff = kqb + (kc << 6);
#pragma unroll
    for (int j = 0; j < 16; ++j) {
      int f = tid + (j << 7);
      int row = f >> 4, c4 = (f & 15) << 2;
      *(float4*)(Wbuf + WROW(row) + c4) =
          *(const float4*)(lw + (size_t)(n0 + row) * 2048 + koff + c4);
    }
#pragma unroll
    for (int j = 0; j < 4; ++j) {
      int f = tid + (j << 7);
      int bi = f >> 4, c4 = (f & 15) << 2;
      *(float4*)(Hbuf + WROW(bi) + c4) =
          *(const float4*)(h_bt + (size_t)bi * 2048 + koff + c4);
    }
    __syncthreads();
#pragma unroll 2
    for (int k4 = 0; k4 < 16; ++k4) {
      int kk = k4 << 2;
      float4 h0 = *(const float4*)(Hbuf + WROW(bb0 + 0) + kk);
      float4 h1 = *(const float4*)(Hbuf + WROW(bb0 + 1) + kk);
      float4 h2 = *(const float4*)(Hbuf + WROW(bb0 + 2) + kk);
      float4 h3 = *(const float4*)(Hbuf + WROW(bb0 + 3) + kk);
#pragma unroll
      for (int j = 0; j < 8; ++j) {
        float4 w4 = *(const float4*)(Wbuf + WROW(nb + j) + kk);
        float s0 = acc[j * 4 + 0], s1 = acc[j * 4 + 1];
        float s2 = acc[j * 4 + 2], s3 = acc[j * 4 + 3];
        s0 = fmaf(w4.x, h0.x, s0); s0 = fmaf(w4.y, h0.y, s0);
        s0 = fmaf(w4.z, h0.z, s0); s0 = fmaf(w4.w, h0.w, s0);
        s1 = fmaf(w4.x, h1.x, s1); s1 = fmaf(w4.y, h1.y, s1);
        s1 = fmaf(w4.z, h1.z, s1); s1 = fmaf(w4.w, h1.w, s1);
        s2 = fmaf(w4.x, h2.x, s2); s2 = fmaf(w4.y, h2.y, s2);
        s2 = fmaf(w4.z, h2.z, s2); s2 = fmaf(w4.w, h2.w, s2);
        s3 = fmaf(w4.x, h3.x, s3); s3 = fmaf(w4.y, h3.y, s3);
        s3 = fmaf(w4.z, h3.z, s3); s3 = fmaf(w4.w, h3.w, s3);
        acc[j * 4 + 0] = s0; acc[j * 4 + 1] = s1;
        acc[j * 4 + 2] = s2; acc[j * 4 + 3] = s3;
      }
    }
    __syncthreads();
  }
#pragma unroll
  for (int i = 0; i < 4; ++i) {
    float* p = qpart + (size_t)q * 1179648 + (size_t)(bb0 + i) * NN + n0 + nb;
    *(float4*)(p + 0) = make_float4(acc[0 * 4 + i], acc[1 * 4 + i], acc[2 * 4 + i], acc[3 * 4 + i]);
    *(float4*)(p + 4) = make_float4(acc[4 * 4 + i], acc[5 * 4 + i], acc[6 * 4 + i], acc[7 * 4 + i]);
  }
}

// ---------------- Stage 3b: combine quarters (exact ((q0+q1)+q2)+q3 + lb) ----------
__global__ __launch_bounds__(256) void combine_kernel(const float* __restrict__ qpart,
                                                      const float* __restrict__ lb,
                                                      float* __restrict__ mats) {
  int blk = blockIdx.x;          // 576 = 32 b x 18 nt
  int b = blk / 18, nt = blk - b * 18;
  int n = (nt << 11) + (threadIdx.x << 3);
  size_t base = (size_t)b * NN + n;
#pragma unroll
  for (int h = 0; h < 2; ++h) {
    float4 q0 = *(const float4*)(qpart + 0 * 1179648 + base + 4 * h);
    float4 q1 = *(const float4*)(qpart + 1 * 1179648 + base + 4 * h);
    float4 q2 = *(const float4*)(qpart + 2 * 1179648 + base + 4 * h);
    float4 q3 = *(const float4*)(qpart + 3 * 1179648 + base + 4 * h);
    float4 bb = *(const float4*)(lb + n + 4 * h);
    float4 o;
    o.x = ((q0.x + q1.x) + q2.x) + q3.x + bb.x;
    o.y = ((q0.y + q1.y) + q2.y) + q3.y + bb.y;
    o.z = ((q0.z + q1.z) + q2.z) + q3.z + bb.z;
    o.w = ((q0.w + q1.w) + q2.w) + q3.w + bb.w;
    *(float4*)(mats + base + 4 * h) = o;
  }
}

// ---------------- Stage 4: BLOCKED LU NB=8, lookahead, fused TRSM, BALANCED B ------
// (R20 verified: 194.5us, absmax 4194304)
#define CAT_(A, B) A##B
#define CAT(A, B) CAT_(A, B)
#define PR_0(R) CAT(pA, R).x
#define PR_1(R) CAT(pA, R).y
#define PR_2(R) CAT(pA, R).z
#define PR_3(R) CAT(pA, R).w
#define PR_4(R) CAT(pB, R).x
#define PR_5(R) CAT(pB, R).y
#define PR_6(R) CAT(pB, R).z
#define PR_7(R) CAT(pB, R).w
#define PR(R, K) CAT(PR_, K)(R)
#define UU_0 uA.x
#define UU_1 uA.y
#define UU_2 uA.z
#define UU_3 uA.w
#define UU_4 uB.x
#define UU_5 uB.y
#define UU_6 uB.z
#define UU_7 uB.w
#define UU(K) CAT(UU_, K)
#define UPDJ(R, J) PR(R, J) = fmaf(-m, UU(J), PR(R, J));
#define TAIL_0(R) UPDJ(R,1) UPDJ(R,2) UPDJ(R,3) UPDJ(R,4) UPDJ(R,5) UPDJ(R,6) UPDJ(R,7)
#define TAIL_1(R) UPDJ(R,2) UPDJ(R,3) UPDJ(R,4) UPDJ(R,5) UPDJ(R,6) UPDJ(R,7)
#define TAIL_2(R) UPDJ(R,3) UPDJ(R,4) UPDJ(R,5) UPDJ(R,6) UPDJ(R,7)
#define TAIL_3(R) UPDJ(R,4) UPDJ(R,5) UPDJ(R,6) UPDJ(R,7)
#define TAIL_4(R) UPDJ(R,5) UPDJ(R,6) UPDJ(R,7)
#define TAIL_5(R) UPDJ(R,6) UPDJ(R,7)
#define TAIL_6(R) UPDJ(R,7)
#define TAIL_7(R)
#define UPDROW(R, KK, kg)                                                      \
  if (CAT(lg, R) > (kg)) {                                                     \
    float m = PR(R, KK) * recip;                                               \
    PR(R, KK) = m;                                                             \
    CAT(TAIL_, KK)(R)                                                          \
  }
#define PSTEP(KK) {                                                            \
  const int kg = kpP + KK;                                                     \
  float bv = -1.f; int br = 0x7fffffff;                                        \
  { float v = fabsf(PR(0,KK)); if (lg0 >= kg && (v > bv || (v == bv && lg0 < br))) { bv = v; br = lg0; } } \
  { float v = fabsf(PR(1,KK)); if (lg1 >= kg && (v > bv || (v == bv && lg1 < br))) { bv = v; br = lg1; } } \
  { float v = fabsf(PR(2,KK)); if (lg2 >= kg && (v > bv || (v == bv && lg2 < br))) { bv = v; br = lg2; } } \
  for (int msk = 1; msk <= 32; msk <<= 1) {                                    \
    float ov = __shfl_xor(bv, msk, 64);                                        \
    int obr = __shfl_xor(br, msk, 64);                                         \
    if (ov > bv || (ov == bv && obr < br)) { bv = ov; br = obr; }              \
  }                                                                            \
  bool own0 = (lg0 == br), own1 = (lg1 == br), own2 = (lg2 == br);             \
  float4 sA = own1 ? pA1 : (own2 ? pA2 : pA0);                                 \
  float4 sB = own1 ? pB1 : (own2 ? pB2 : pB0);                                 \
  int owner = (int)__ffsll(__ballot(own0 | own1 | own2)) - 1;                  \
  float4 uA, uB;                                                               \
  uA.x = __shfl(sA.x, owner); uA.y = __shfl(sA.y, owner);                      \
  uA.z = __shfl(sA.z, owner); uA.w = __shfl(sA.w, owner);                      \
  uB.x = __shfl(sB.x, owner); uB.y = __shfl(sB.y, owner);                      \
  uB.z = __shfl(sB.z, owner); uB.w = __shfl(sB.w, owner);                      \
  float piv = UU(KK);                                                          \
  float recip = 1.0f / piv;                                                    \
  if (tid == 0) {                                                              \
    diagU[kg] = piv;                                                           \
    int t0 = rowmap[kg], t1 = rowmap[br];                                      \
    rowmap[kg] = t1; rowmap[br] = t0;                                          \
  }                                                                            \
  lg0 = (lg0 == kg) ? br : ((lg0 == br) ? kg : lg0);                           \
  lg1 = (lg1 == kg) ? br : ((lg1 == br) ? kg : lg1);                           \
  lg2 = (lg2 == kg) ? br : ((lg2 == br) ? kg : lg2);                           \
  UPDROW(0, KK, kg)                                                            \
  UPDROW(1, KK, kg)                                                            \
  UPDROW(2, KK, kg)                                                            \
}
#define FMA4(D, M, S) {                                                        \
  float mm = (M);                                                              \
  D.x = fmaf(-mm, S.x, D.x); D.y = fmaf(-mm, S.y, D.y);                        \
  D.z = fmaf(-mm, S.z, D.z); D.w = fmaf(-mm, S.w, D.w);                        \
}
// panel factorization of cols [KPV, KPV+8), wave 0 only, all in registers
#define PANEL(KPV) {                                                           \
  const int kpP = (KPV);                                                       \
  const int pcP = kpP >> 2;                                                    \
  float4 pA0 = As4[tid * 49 + pcP],         pB0 = As4[tid * 49 + pcP + 1];     \
  float4 pA1 = As4[(tid + 64) * 49 + pcP],  pB1 = As4[(tid + 64) * 49 + pcP + 1]; \
  float4 pA2 = As4[(tid + 128) * 49 + pcP], pB2 = As4[(tid + 128) * 49 + pcP + 1]; \
  PSTEP(0) PSTEP(1) PSTEP(2) PSTEP(3) PSTEP(4) PSTEP(5) PSTEP(6) PSTEP(7)     \
  As4[tid * 49 + pcP] = pA0;         As4[tid * 49 + pcP + 1] = pB0;            \
  As4[(tid + 64) * 49 + pcP] = pA1;  As4[(tid + 64) * 49 + pcP + 1] = pB1;     \
  As4[(tid + 128) * 49 + pcP] = pA2; As4[(tid + 128) * 49 + pcP + 1] = pB2;    \
}
// TRSM of the 8 u-rows for chunk COLQ, entirely in registers (defines u40..u47).
#define TRSM8REG(U0, U1, U2, U3, U4, U5, U6, U7, COLQ)                         \
  float4 u40 = As4[U0 * 49 + (COLQ)], u41 = As4[U1 * 49 + (COLQ)];             \
  float4 u42 = As4[U2 * 49 + (COLQ)], u43 = As4[U3 * 49 + (COLQ)];             \
  float4 u44 = As4[U4 * 49 + (COLQ)], u45 = As4[U5 * 49 + (COLQ)];             \
  float4 u46 = As4[U6 * 49 + (COLQ)], u47 = As4[U7 * 49 + (COLQ)];             \
  { float4 la = As4[U1 * 49 + pc];                                             \
    FMA4(u41, la.x, u40) }                                                     \
  { float4 la = As4[U2 * 49 + pc];                                             \
    FMA4(u42, la.x, u40) FMA4(u42, la.y, u41) }                                \
  { float4 la = As4[U3 * 49 + pc];                                             \
    FMA4(u43, la.x, u40) FMA4(u43, la.y, u41) FMA4(u43, la.z, u42) }           \
  { float4 la = As4[U4 * 49 + pc];                                             \
    FMA4(u44, la.x, u40) FMA4(u44, la.y, u41) FMA4(u44, la.z, u42) FMA4(u44, la.w, u43) } \
  { float4 la = As4[U5 * 49 + pc]; float4 lb2 = As4[U5 * 49 + pc + 1];         \
    FMA4(u45, la.x, u40) FMA4(u45, la.y, u41) FMA4(u45, la.z, u42) FMA4(u45, la.w, u43) \
    FMA4(u45, lb2.x, u44) }                                                    \
  { float4 la = As4[U6 * 49 + pc]; float4 lb2 = As4[U6 * 49 + pc + 1];         \
    FMA4(u46, la.x, u40) FMA4(u46, la.y, u41) FMA4(u46, la.z, u42) FMA4(u46, la.w, u43) \
    FMA4(u46, lb2.x, u44) FMA4(u46, lb2.y, u45) }                              \
  { float4 la = As4[U7 * 49 + pc]; float4 lb2 = As4[U7 * 49 + pc + 1];         \
    FMA4(u47, la.x, u40) FMA4(u47, la.y, u41) FMA4(u47, la.z, u42) FMA4(u47, la.w, u43) \
    FMA4(u47, lb2.x, u44) FMA4(u47, lb2.y, u45) FMA4(u47, lb2.z, u46) }

__global__ __launch_bounds__(768, 1) void lu_kernel(float* __restrict__ A0,
                                                    const float* __restrict__ ssign,
                                                    float* __restrict__ ssum) {
  __shared__ float4 As4[192 * 49];     // 150528 B, row stride 49 float4
  __shared__ int rowmap[192];
  __shared__ float diagU[192];
  __shared__ float4 dval4[48];
  float* dvalf = (float*)dval4;
  int b = blockIdx.x;
  int tid = threadIdx.x;
  float* __restrict__ A = A0 + (size_t)b * NN;

#pragma unroll
  for (int j = 0; j < 12; ++j) {
    int chunk = tid + 768 * j;
    int row = chunk / 48, q = chunk - row * 48;
    As4[row * 49 + q] = *(const float4*)(A + row * 192 + 4 * q);
  }
  for (int i = tid; i < 192; i += 768) rowmap[i] = i;
  __syncthreads();

  int lg0 = tid, lg1 = tid + 64, lg2 = tid + 128;   // logical pos of wave0's rows

  // prologue: factorize panel 0
  if (tid < 64) { PANEL(0) }
  __syncthreads();

  const int slot = tid & 15;

  for (int p = 0; p < 23; ++p) {
    const int kp = p << 3;
    const int pc = kp >> 2;
    const int qp1 = pc + 2;      // first trailing chunk (= next panel's cols)

    // ---- phase A: TRSM-in-reg + GEMM next panel's 2 chunk cols + snapshot ----
    {
      const int col = qp1 + (tid >= 384 ? 1 : 0);
      const int rsl = tid - (tid >= 384 ? 384 : 0);
      const int s = kp + 8 + rsl;
      if (s < 192) {
        const int ua0 = rowmap[kp + 0], ua1 = rowmap[kp + 1];
        const int ua2 = rowmap[kp + 2], ua3 = rowmap[kp + 3];
        const int ua4 = rowmap[kp + 4], ua5 = rowmap[kp + 5];
        const int ua6 = rowmap[kp + 6], ua7 = rowmap[kp + 7];
        TRSM8REG(ua0, ua1, ua2, ua3, ua4, ua5, ua6, ua7, col)
        int phys = rowmap[s];
        float4 la = As4[phys * 49 + pc];
        float4 lb2 = As4[phys * 49 + pc + 1];
        float4 c = As4[phys * 49 + col];
        FMA4(c, la.x, u40) FMA4(c, la.y, u41) FMA4(c, la.z, u42) FMA4(c, la.w, u43)
        FMA4(c, lb2.x, u44) FMA4(c, lb2.y, u45) FMA4(c, lb2.z, u46) FMA4(c, lb2.w, u47)
        As4[phys * 49 + col] = c;
      }
    }
    // snapshot phys rows for phase B (named regs; rowmap stable until bar1)
    int php0, php1, php2, php3, php4, php5, php6, php7, php8, php9, php10, php11;
#define SNAP(I) CAT(php, I) = rowmap[slot + (I << 4)];
    SNAP(0) SNAP(1) SNAP(2) SNAP(3) SNAP(4) SNAP(5) SNAP(6)
    SNAP(7) SNAP(8) SNAP(9) SNAP(10) SNAP(11)
#undef SNAP
    __syncthreads();  // bar1: next-panel cols GEMM'd; snapshots taken

    // ---- phase B: wave0 panel p+1 || others balanced TRSM+GEMM ----
    if (tid < 64) {
      PANEL(kp + 8)
    } else {
      const int ncols = 44 - pc;            // trailing chunk cols pc+4..47
      if (ncols > 0) {
        const int g = (tid >> 4) - 4;       // 0..43
        const int nparts = 44 / ncols;      // >= 1
        const int part = g / ncols;
        const int colIdx = g - part * ncols;
        if (part < nparts) {
          const int q = pc + 4 + colIdx;
          const int ub0 = rowmap[kp + 0], ub1 = rowmap[kp + 1];
          const int ub2 = rowmap[kp + 2], ub3 = rowmap[kp + 3];
          const int ub4 = rowmap[kp + 4], ub5 = rowmap[kp + 5];
          const int ub6 = rowmap[kp + 6], ub7 = rowmap[kp + 7];
          TRSM8REG(ub0, ub1, ub2, ub3, ub4, ub5, ub6, ub7, q)
#define GEMMROW(I) {                                                           \
          int s = slot + (I << 4);                                             \
          if ((I % nparts) == part && s >= kp + 8) {                           \
            int phys = CAT(php, I);                                            \
            float4 la = As4[phys * 49 + pc];                                   \
            float4 lb2 = As4[phys * 49 + pc + 1];                              \
            float4 c = As4[phys * 49 + q];                                     \
            FMA4(c, la.x, u40) FMA4(c, la.y, u41) FMA4(c, la.z, u42) FMA4(c, la.w, u43) \
            FMA4(c, lb2.x, u44) FMA4(c, lb2.y, u45) FMA4(c, lb2.z, u46) FMA4(c, lb2.w, u47) \
            As4[phys * 49 + q] = c;                                            \
          }                                                                    \
        }
          GEMMROW(0) GEMMROW(1) GEMMROW(2) GEMMROW(3) GEMMROW(4) GEMMROW(5)
          GEMMROW(6) GEMMROW(7) GEMMROW(8) GEMMROW(9) GEMMROW(10) GEMMROW(11)
#undef GEMMROW
        }
      }
    }
    __syncthreads();  // bar2: panel p+1 factorized; trailing(p) complete
  }

  // ---- epilogue: logdet partial, dval, weight = mats + P*(L*diag(d)) ----
  if (tid == 0) {
    float s = 0.f;
    for (int i = 0; i < 192; ++i) s += diagU[i];
    ssum[b] = s;
  }
  if (tid < 192) dvalf[tid] = ssign[tid] * expf(diagU[tid]) - diagU[tid];
  __syncthreads();
  {
    const int r = tid >> 2;
    const int tq = tid & 3;
    int i = r;
    int phys = rowmap[r];
    float di = dvalf[i];
    float* __restrict__ G = A + (size_t)phys * 192;   // output row = original row phys
    int qi = i >> 2;
    for (int j = 0; j < 12; ++j) {
      int q = tq + 4 * j;
      if (q > qi) continue;
      float4 g4 = *(float4*)(G + 4 * q);
      float4 a4 = As4[phys * 49 + q];
      float4 d4 = dval4[q];
      if (q == qi) {
        int c0 = 4 * q;
        g4.x = (c0 + 0 < i) ? g4.x + a4.x * d4.x : ((c0 + 0 == i) ? g4.x + di : g4.x);
        g4.y = (c0 + 1 < i) ? g4.y + a4.y * d4.y : ((c0 + 1 == i) ? g4.y + di : g4.y);
        g4.z = (c0 + 2 < i) ? g4.z + a4.z * d4.z : ((c0 + 2 == i) ? g4.z + di : g4.z);
        g4.w = (c0 + 3 < i) ? g4.w + a4.w * d4.w : ((c0 + 3 == i) ? g4.w + di : g4.w);
      } else {
        g4.x += a4.x * d4.x;
        g4.y += a4.y * d4.y;
        g4.z += a4.z * d4.z;
        g4.w += a4.w * d4.w;
      }
      *(float4*)(G + 4 * q) = g4;
    }
  }
}

// ---------------- Stage 5: out[b] = weight[b] @ inp[b]  (+ logdet write) ----------
// (R19 verified: W transposed staging, 3 LDS instr / 32 FMA, bit-exact)
__global__ __launch_bounds__(256) void out_kernel(const float* __restrict__ wt,
                                                  const float* __restrict__ inp,
                                                  const float* __restrict__ ssum,
                                                  float* __restrict__ out) {
  int blk = blockIdx.x;
  int b = blk / 24, rem = blk % 24;
  int it = rem >> 3, jt = rem & 7;
  int i0 = it << 6, hw0 = jt << 7;
  int tid = threadIdx.x;
  int tx = tid & 31, ty = tid >> 5;
  __shared__ float wldsT[32 * 68];   // [k][i] transposed, stride 68 (16B-aligned)
  __shared__ float xlds[32 * 128];
  const float* wb = wt + (size_t)b * NN;
  const float* xb = inp + (((size_t)b * 192) << 10);
  float acc[8][4];
#pragma unroll
  for (int r = 0; r < 8; ++r)
#pragma unroll
    for (int c = 0; c < 4; ++c) acc[r][c] = 0.f;
  for (int kc = 0; kc < 6; ++kc) {
    __syncthreads();
#pragma unroll
    for (int j = 0; j < 2; ++j) {
      int f4 = tid + (j << 8);
      int row = f4 >> 3, c4 = (f4 & 7) << 2;
      float4 v = *(const float4*)(wb + (size_t)(i0 + row) * 192 + (kc << 5) + c4);
      wldsT[(c4 + 0) * 68 + row] = v.x;
      wldsT[(c4 + 1) * 68 + row] = v.y;
      wldsT[(c4 + 2) * 68 + row] = v.z;
      wldsT[(c4 + 3) * 68 + row] = v.w;
    }
#pragma unroll
    for (int j = 0; j < 4; ++j) {
      int f4 = tid + (j << 8);
      int row = f4 >> 5, c4 = (f4 & 31) << 2;
      float4 v = *(const float4*)(xb + (((size_t)(kc << 5) + row) << 10) + hw0 + c4);
      *(float4*)(xlds + (row << 7) + c4) = v;
    }
    __syncthreads();
#pragma unroll 4
    for (int k = 0; k < 32; ++k) {
      float4 xv = *(const float4*)(xlds + (k << 7) + (tx << 2));
      float4 wa = *(const float4*)(wldsT + k * 68 + ty * 8);
      float4 wbv = *(const float4*)(wldsT + k * 68 + ty * 8 + 4);
      acc[0][0] = fmaf(wa.x, xv.x, acc[0][0]);
      acc[0][1] = fmaf(wa.x, xv.y, acc[0][1]);
      acc[0][2] = fmaf(wa.x, xv.z, acc[0][2]);
      acc[0][3] = fmaf(wa.x, xv.w, acc[0][3]);
      acc[1][0] = fmaf(wa.y, xv.x, acc[1][0]);
      acc[1][1] = fmaf(wa.y, xv.y, acc[1][1]);
      acc[1][2] = fmaf(wa.y, xv.z, acc[1][2]);
      acc[1][3] = fmaf(wa.y, xv.w, acc[1][3]);
      acc[2][0] = fmaf(wa.z, xv.x, acc[2][0]);
      acc[2][1] = fmaf(wa.z, xv.y, acc[2][1]);
      acc[2][2] = fmaf(wa.z, xv.z, acc[2][2]);
      acc[2][3] = fmaf(wa.z, xv.w, acc[2][3]);
      acc[3][0] = fmaf(wa.w, xv.x, acc[3][0]);
      acc[3][1] = fmaf(wa.w, xv.y, acc[3][1]);
      acc[3][2] = fmaf(wa.w, xv.z, acc[3][2]);
      acc[3][3] = fmaf(wa.w, xv.w, acc[3][3]);
      acc[4][0] = fmaf(wbv.x, xv.x, acc[4][0]);
      acc[4][1] = fmaf(wbv.x, xv.y, acc[4][1]);
      acc[4][2] = fmaf(wbv.x, xv.z, acc[4][2]);
      acc[4][3] = fmaf(wbv.x, xv.w, acc[4][3]);
      acc[5][0] = fmaf(wbv.y, xv.x, acc[5][0]);
      acc[5][1] = fmaf(wbv.y, xv.y, acc[5][1]);
      acc[5][2] = fmaf(wbv.y, xv.z, acc[5][2]);
      acc[5][3] = fmaf(wbv.y, xv.w, acc[5][3]);
      acc[6][0] = fmaf(wbv.z, xv.x, acc[6][0]);
      acc[6][1] = fmaf(wbv.z, xv.y, acc[6][1]);
      acc[6][2] = fmaf(wbv.z, xv.z, acc[6][2]);
      acc[6][3] = fmaf(wbv.z, xv.w, acc[6][3]);
      acc[7][0] = fmaf(wbv.w, xv.x, acc[7][0]);
      acc[7][1] = fmaf(wbv.w, xv.y, acc[7][1]);
      acc[7][2] = fmaf(wbv.w, xv.z, acc[7][2]);
      acc[7][3] = fmaf(wbv.w, xv.w, acc[7][3]);
    }
  }
  float* ob = out + (((size_t)b * 192 + i0 + ty * 8) << 10) + hw0 + (tx << 2);
#pragma unroll
  for (int r = 0; r < 8; ++r) {
    float4 v = make_float4(acc[r][0], acc[r][1], acc[r][2], acc[r][3]);
    *(float4*)(ob + ((size_t)r << 10)) = v;
  }
  if (blk == 0 && tid == 0) {
    float s = 0.f;
    for (int i = 0; i < 32; ++i) s += ssum[i];
    out[6291456] = 32.f * s;   // H*W * mean over batch of sum(s)
  }
}

extern "C" void kernel_launch(void* const* d_in, const int* in_sizes, int n_in,
                              void* d_out, int out_size, void* d_ws, size_t ws_size,
                              hipStream_t stream) {
  const float* inp = (const float*)d_in[0];
  const float* wlo = (const float*)d_in[1];
  const float* cw  = (const float*)d_in[2];
  const float* cb  = (const float*)d_in[3];
  const float* lw  = (const float*)d_in[4];
  const float* lb  = (const float*)d_in[5];
  const float* ss  = (const float*)d_in[6];
  float* out = (float*)d_out;
  float* ws = (float*)d_ws;
  // ws layout (floats): hpart 262144 | h_bt 65536 | mats 1179648 | ssum 32  (~6 MB)
  // quarter partials (18.9 MB) live in d_out and are overwritten by out_kernel.
  float* hpart = ws;
  float* h_bt  = ws + 262144;
  float* mats  = ws + 327680;
  float* ssum  = ws + 1507328;
  float* qpart = out;
  hipLaunchKernelGGL(conv_kernel,    dim3(256),  dim3(256), 0, stream, wlo, cw, hpart);
  hipLaunchKernelGGL(hreduce_kernel, dim3(256),  dim3(256), 0, stream, hpart, cb, h_bt);
  hipLaunchKernelGGL(linear_kernel,  dim3(1152), dim3(128), 0, stream, h_bt, lw, qpart);
  hipLaunchKernelGGL(combine_kernel, dim3(576),  dim3(256), 0, stream, qpart, lb, mats);
  hipLaunchKernelGGL(lu_kernel,      dim3(32),   dim3(768), 0, stream, mats, ss, ssum);
  hipLaunchKernelGGL(out_kernel,     dim3(768),  dim3(256), 0, stream, mats, inp, ssum, out);
}